// Round 14
// baseline (2078.398 us; speedup 1.0000x reference)
//
#include <hip/hip_runtime.h>
#include <hip/hip_bf16.h>
#include <cstddef>
#include <cstdint>

#define N_NODES 50000
#define N_EDGES 800000
#define N_REL 8
#define F_IN 256
#define F_HID 512
#define F_OUT 128
#define KT1 (N_REL * F_IN + F_IN)    // 2304
#define NC2P 1280                    // padded layer-2 cols (1152 used)
#define NSEG (N_NODES * N_REL)       // 400000
#define SCAN_NB ((NSEG + 1023) / 1024) // 391

typedef __attribute__((ext_vector_type(8))) short short8;
typedef __attribute__((ext_vector_type(4))) float f32x4;

__device__ __forceinline__ float bf2f(unsigned short u) {
    return __uint_as_float(((unsigned)u) << 16);
}
__device__ __forceinline__ unsigned short f2bf(float f) {
    __hip_bfloat16 h = __float2bfloat16(f);
    return *reinterpret_cast<unsigned short*>(&h);
}

// ---------- int64-vs-int32 edge dtype detection ----------
__global__ void detect64_kernel(const int* __restrict__ et, int* __restrict__ flag) {
    int v = et[2 * threadIdx.x + 1];
    unsigned long long any = __ballot(v != 0);
    if (threadIdx.x == 0) flag[0] = (any == 0ULL) ? 1 : 0;
}

__device__ __forceinline__ long long ld_idx(const void* __restrict__ p, size_t i, int is64) {
    return is64 ? ((const long long*)p)[i] : (long long)((const int*)p)[i];
}

__global__ void count_kernel(const void* __restrict__ etype, const void* __restrict__ eidx,
                             const int* __restrict__ flag, unsigned* __restrict__ cnt8) {
    int e = blockIdx.x * blockDim.x + threadIdx.x;
    if (e >= N_EDGES) return;
    int is64 = flag[0];
    long long rt  = ld_idx(etype, e, is64);
    long long dst = ld_idx(eidx, (size_t)N_EDGES + e, is64);
    atomicAdd(&cnt8[dst * N_REL + rt], 1u);
}

// ---------- parallel seg-level exclusive scan (3 kernels) + invc ----------
__global__ __launch_bounds__(1024) void scan1_kernel(const unsigned* __restrict__ cnt8,
                                                     float* __restrict__ invc,
                                                     int* __restrict__ soff,
                                                     int* __restrict__ bsum) {
    __shared__ int lds[1024];
    int t = threadIdx.x;
    int i = blockIdx.x * 1024 + t;
    int c = (i < NSEG) ? (int)cnt8[i] : 0;
    if (i < NSEG) invc[i] = 1.0f / (float)(c ? c : 1);
    lds[t] = c;
    __syncthreads();
    for (int o = 1; o < 1024; o <<= 1) {
        int v = (t >= o) ? lds[t - o] : 0;
        __syncthreads();
        lds[t] += v;
        __syncthreads();
    }
    if (i < NSEG) soff[i] = lds[t] - c;
    if (t == 1023) bsum[blockIdx.x] = lds[1023];
}

__global__ __launch_bounds__(512) void scan2_kernel(int* __restrict__ bsum) {
    __shared__ int lds[512];
    int t = threadIdx.x;
    int v = (t < SCAN_NB) ? bsum[t] : 0;
    lds[t] = v;
    __syncthreads();
    for (int o = 1; o < 512; o <<= 1) {
        int x = (t >= o) ? lds[t - o] : 0;
        __syncthreads();
        lds[t] += x;
        __syncthreads();
    }
    if (t < SCAN_NB) bsum[t] = lds[t] - v;
}

__global__ void scan3_kernel(int* __restrict__ soff, const int* __restrict__ bsum) {
    int g = blockIdx.x * blockDim.x + threadIdx.x;
    if (g < NSEG) soff[g] += bsum[g >> 10];
    if (g == 0) soff[NSEG] = N_EDGES;
}

// ---------- bucket edges into seg-sorted CSR: ebuf[pos] = src ----------
__global__ void build_kernel(const void* __restrict__ eidx, const void* __restrict__ etype,
                             const int* __restrict__ flag, const int* __restrict__ soff,
                             int* __restrict__ cursor, unsigned* __restrict__ ebuf) {
    int e = blockIdx.x * blockDim.x + threadIdx.x;
    if (e >= N_EDGES) return;
    int is64 = flag[0];
    int rt  = (int)ld_idx(etype, e, is64);
    int src = (int)ld_idx(eidx, e, is64);
    int dst = (int)ld_idx(eidx, (size_t)N_EDGES + e, is64);
    int seg = dst * N_REL + rt;
    int pos = soff[seg] + atomicAdd(&cursor[seg], 1);
    ebuf[pos] = (unsigned)src;
}

__global__ void cvt_bf16_kernel(const float* __restrict__ in, __hip_bfloat16* __restrict__ out,
                                long long n4) {
    long long g = (long long)blockIdx.x * blockDim.x + threadIdx.x;
    if (g >= n4) return;
    float4 v = ((const float4*)in)[g];
    unsigned short o[4];
    o[0] = f2bf(v.x); o[1] = f2bf(v.y); o[2] = f2bf(v.z); o[3] = f2bf(v.w);
    *(short4*)&out[4 * g] = *(const short4*)o;
}

// ---------- fused LDS-tiled weight transposes ----------
__global__ __launch_bounds__(256) void trans_w_kernel(
    const float* __restrict__ w1, const float* __restrict__ root1,
    const float* __restrict__ w2, const float* __restrict__ root2,
    __hip_bfloat16* __restrict__ bt1, __hip_bfloat16* __restrict__ bt2)
{
    __shared__ float t[32][33];
    int tx = threadIdx.x & 31, ty = threadIdx.x >> 5;
    int b = blockIdx.x;
    if (b < 9 * 128) {
        int r  = b >> 7;
        int rem = b & 127;
        int kt = rem >> 4, nt = rem & 15;
        const float* src = (r < 8) ? (w1 + (size_t)r * F_IN * F_HID) : root1;
        int k0 = kt * 32, n0 = nt * 32;
        #pragma unroll
        for (int i = 0; i < 4; ++i)
            t[ty + i * 8][tx] = src[(size_t)(k0 + ty + i * 8) * F_HID + n0 + tx];
        __syncthreads();
        #pragma unroll
        for (int i = 0; i < 4; ++i) {
            int n = n0 + ty + i * 8;
            bt1[(size_t)n * KT1 + r * F_IN + k0 + tx] = __float2bfloat16(t[tx][ty + i * 8]);
        }
    } else {
        b -= 9 * 128;
        int r  = b >> 6;
        int rem = b & 63;
        int kt = rem >> 2, ot = rem & 3;
        const float* src = (r < 8) ? (w2 + (size_t)r * F_HID * F_OUT) : root2;
        int k0 = kt * 32, o0 = ot * 32;
        #pragma unroll
        for (int i = 0; i < 4; ++i)
            t[ty + i * 8][tx] = src[(size_t)(k0 + ty + i * 8) * F_OUT + o0 + tx];
        __syncthreads();
        #pragma unroll
        for (int i = 0; i < 4; ++i) {
            int o = o0 + ty + i * 8;
            bt2[(size_t)(r * F_OUT + o) * F_HID + k0 + tx] = __float2bfloat16(t[tx][ty + i * 8]);
        }
    }
}

// ---------- layer-1 gather ----------
template <int CR>
__global__ __launch_bounds__(256) void gather1_kernel(
    const __hip_bfloat16* __restrict__ xb, const unsigned* __restrict__ ebuf,
    const int* __restrict__ soff, const float* __restrict__ invc,
    __hip_bfloat16* __restrict__ aggb, int r0)
{
    int wid  = (blockIdx.x * blockDim.x + threadIdx.x) >> 6;
    int lane = threadIdx.x & 63;
    if (wid >= N_NODES) return;
    const int* sp = soff + wid * N_REL + r0;
    int s[CR + 1];
    #pragma unroll
    for (int c = 0; c <= CR; ++c) s[c] = sp[c];

    #pragma unroll
    for (int c = 0; c < CR; ++c) {
        int e0 = s[c], e1 = s[c + 1];
        float a0 = 0.f, a1 = 0.f, a2 = 0.f, a3 = 0.f;
        int e = e0;
        for (; e + 2 <= e1; e += 2) {
            unsigned s0 = ebuf[e], s1 = ebuf[e + 1];
            short4 v0 = *(const short4*)&xb[(size_t)s0 * F_IN + lane * 4];
            short4 v1 = *(const short4*)&xb[(size_t)s1 * F_IN + lane * 4];
            a0 += bf2f((unsigned short)v0.x) + bf2f((unsigned short)v1.x);
            a1 += bf2f((unsigned short)v0.y) + bf2f((unsigned short)v1.y);
            a2 += bf2f((unsigned short)v0.z) + bf2f((unsigned short)v1.z);
            a3 += bf2f((unsigned short)v0.w) + bf2f((unsigned short)v1.w);
        }
        if (e < e1) {
            unsigned s0 = ebuf[e];
            short4 v0 = *(const short4*)&xb[(size_t)s0 * F_IN + lane * 4];
            a0 += bf2f((unsigned short)v0.x);
            a1 += bf2f((unsigned short)v0.y);
            a2 += bf2f((unsigned short)v0.z);
            a3 += bf2f((unsigned short)v0.w);
        }
        float sc = invc[(size_t)wid * N_REL + r0 + c];
        unsigned short o[4];
        o[0] = f2bf(a0 * sc); o[1] = f2bf(a1 * sc);
        o[2] = f2bf(a2 * sc); o[3] = f2bf(a3 * sc);
        *(short4*)&aggb[((size_t)wid * CR + c) * F_IN + lane * 4] = *(const short4*)o;
    }
}

// ---------- layer-2 gather + root + bias + log_softmax ----------
__global__ __launch_bounds__(256) void gather2_kernel(
    const __hip_bfloat16* __restrict__ z, const unsigned* __restrict__ ebuf,
    const int* __restrict__ soff, const float* __restrict__ invc,
    const float* __restrict__ b2, float* __restrict__ h)
{
    int wid  = (blockIdx.x * blockDim.x + threadIdx.x) >> 6;
    int lane = threadIdx.x & 63;
    if (wid >= N_NODES) return;
    const int* sp = soff + wid * N_REL;
    int s[N_REL + 1];
    #pragma unroll
    for (int c = 0; c <= N_REL; ++c) s[c] = sp[c];

    unsigned rv = *(const unsigned*)&z[(size_t)wid * NC2P + N_REL * F_OUT + lane * 2];
    float a0 = bf2f((unsigned short)(rv & 0xffffu)) + b2[lane * 2];
    float a1 = bf2f((unsigned short)(rv >> 16))     + b2[lane * 2 + 1];

    #pragma unroll
    for (int c = 0; c < N_REL; ++c) {
        int e0 = s[c], e1 = s[c + 1];
        float t0 = 0.f, t1 = 0.f;
        const size_t coloff = (size_t)c * F_OUT + lane * 2;
        int e = e0;
        for (; e + 2 <= e1; e += 2) {
            unsigned s0 = ebuf[e], s1 = ebuf[e + 1];
            unsigned pv0 = *(const unsigned*)&z[(size_t)s0 * NC2P + coloff];
            unsigned pv1 = *(const unsigned*)&z[(size_t)s1 * NC2P + coloff];
            t0 += bf2f((unsigned short)(pv0 & 0xffffu)) + bf2f((unsigned short)(pv1 & 0xffffu));
            t1 += bf2f((unsigned short)(pv0 >> 16))     + bf2f((unsigned short)(pv1 >> 16));
        }
        if (e < e1) {
            unsigned s0 = ebuf[e];
            unsigned pv0 = *(const unsigned*)&z[(size_t)s0 * NC2P + coloff];
            t0 += bf2f((unsigned short)(pv0 & 0xffffu));
            t1 += bf2f((unsigned short)(pv0 >> 16));
        }
        float sc = invc[(size_t)wid * N_REL + c];
        a0 = fmaf(sc, t0, a0);
        a1 = fmaf(sc, t1, a1);
    }

    float m = fmaxf(a0, a1);
    #pragma unroll
    for (int o = 32; o > 0; o >>= 1) m = fmaxf(m, __shfl_xor(m, o));
    float sum = expf(a0 - m) + expf(a1 - m);
    #pragma unroll
    for (int o = 32; o > 0; o >>= 1) sum += __shfl_xor(sum, o);
    float lse = m + logf(sum);
    h[(size_t)wid * F_OUT + lane * 2]     = a0 - lse;
    h[(size_t)wid * F_OUT + lane * 2 + 1] = a1 - lse;
}

#define BARX do { __builtin_amdgcn_s_barrier(); __builtin_amdgcn_sched_barrier(0); } while (0)
#define VMW(N) asm volatile("s_waitcnt vmcnt(" #N ")" ::: "memory")

// ===== 256x256 8-wave 8-phase GEMM, BK=32, 64KB LDS -> 2 blocks/CU =====
// Same verified phase skeleton as R9-R13, all load counts halved:
// half-tile (128 rows x 32k) = 1 gload_lds/thread; counted VMW(2) at ph4/ph8.
// Ledger (steady state, oldest first at ph4 VMW: [B(kt1)2][A(kt1)2][B(kt0+2)2]
// -> retire 4, buf1 ready, 2 in flight; symmetric at ph8). Write-after-read
// separations identical to BK=64 version (>=1 barrier).
// T2 swizzle for 64B rows: src col ((tid&3)^((tid>>2)&3))*8, read col
// (ksel^(r15&3))*8 -> even/odd rows split bank halves, b128-floor access.
#define QBM 256
#define QBN 256
#define QBK 32

#define MQ8(QR, QC) do {                                                           \
    __builtin_amdgcn_s_setprio(1);                                                 \
    _Pragma("unroll") for (int i2 = 0; i2 < 4; ++i2)                               \
    _Pragma("unroll") for (int j2 = 0; j2 < 2; ++j2)                               \
        acc[(QR)*4 + i2][(QC)*2 + j2] = __builtin_amdgcn_mfma_f32_16x16x32_bf16(   \
            a[i2], b[(QC)*2 + j2], acc[(QR)*4 + i2][(QC)*2 + j2], 0, 0, 0);        \
    __builtin_amdgcn_s_setprio(0); } while (0)

__global__ __launch_bounds__(512, 4) void gemm256_kernel(
    const __hip_bfloat16* __restrict__ A1, int K1, int lda1,
    const __hip_bfloat16* __restrict__ A2, int K2, int lda2,
    const __hip_bfloat16* __restrict__ BTa, const __hip_bfloat16* __restrict__ BTb, int ldbt,
    const float* __restrict__ bias,
    float* __restrict__ Cf, __hip_bfloat16* __restrict__ Cb,
    int M, int Nc, int accumulate, int do_relu,
    int gridX, int nwg)
{
    __shared__ __align__(16) __hip_bfloat16 As[2][QBM * QBK];   // 2 x 16 KB
    __shared__ __align__(16) __hip_bfloat16 Bs[2][QBN * QBK];   // 2 x 16 KB

    int bid = blockIdx.x;
    int qq = nwg >> 3, rr = nwg & 7;
    int xcd = bid & 7, ii = bid >> 3;
    int wg = (xcd < rr ? xcd * (qq + 1) : rr * (qq + 1) + (xcd - rr) * qq) + ii;
    const int bm = (wg / gridX) * QBM;
    const int bn = (wg % gridX) * QBN;

    const int tid  = threadIdx.x;
    const int lane = tid & 63;
    const int wv   = tid >> 6;
    const int wr   = wv >> 2;       // 0..1 (M half, 128 rows)
    const int wc   = wv & 3;        // 0..3 (64-col strip)
    const int r15  = lane & 15;
    const int ksel = lane >> 4;

    // staging: thread -> (row = tid>>2 within half, slot = tid&3); src col swizzled
    const int srow = tid >> 2;                            // 0..127
    const int swz8 = (((tid & 3) ^ (srow & 3))) * 8;      // bf16 col within 32
    // read-side col (elements): (ksel ^ (row&3))*8, row&3 == r15&3
    const int rcol = ((ksel ^ (r15 & 3))) * 8;

    const int Ktot = K1 + K2;
    const int nT   = Ktot / QBK;    // 72 (layer1 CR=8), 40 (CR=4), 16 (layer2) — even
    const int nIt  = nT / 2;

    auto stageA = [&](int kt, int bi, int hh) {
        int k0 = kt * QBK;
        const __hip_bfloat16* base = A1; int ld = lda1;
        if (k0 >= K1) { base = A2; ld = lda2; k0 -= K1; }
        int gr = bm + hh * 128 + srow; if (gr >= M) gr = M - 1;
        const __hip_bfloat16* gp = base + (size_t)gr * ld + k0 + swz8;
        __builtin_amdgcn_global_load_lds(
            (const __attribute__((address_space(1))) void*)gp,
            (__attribute__((address_space(3))) void*)&As[bi][hh * 4096 + tid * 8], 16, 0, 0);
    };
    auto stageB = [&](int kt, int bi, int hh) {
        int k0 = kt * QBK;
        const __hip_bfloat16* base = BTa;
        if (k0 >= K1) { base = BTb; k0 -= K1; }
        int n0 = bn + hh * 128 + srow;
        const __hip_bfloat16* gp = base + (size_t)n0 * ldbt + k0 + swz8;
        __builtin_amdgcn_global_load_lds(
            (const __attribute__((address_space(1))) void*)gp,
            (__attribute__((address_space(3))) void*)&Bs[bi][hh * 4096 + tid * 8], 16, 0, 0);
    };

    short8 a[4], b[4];
    auto loadA4 = [&](int bi, int qr) {
        #pragma unroll
        for (int i2 = 0; i2 < 4; ++i2)
            a[i2] = *(const short8*)&As[bi][(wr * 128 + (qr * 4 + i2) * 16 + r15) * 32 + rcol];
    };
    auto loadB2q = [&](int bi, int qc) {
        #pragma unroll
        for (int j2 = 0; j2 < 2; ++j2)
            b[qc * 2 + j2] = *(const short8*)&Bs[bi][((wc >> 1) * 128 + (wc & 1) * 64 +
                                 (qc * 2 + j2) * 16 + r15) * 32 + rcol];
    };

    f32x4 acc[8][4] = {};

    // prologue: kt0 full (4 insts) + B(kt1) (2 insts); VMW(2) -> kt0 complete
    stageA(0, 0, 0); stageA(0, 0, 1); stageB(0, 0, 0); stageB(0, 0, 1);
    stageB(1, 1, 0); stageB(1, 1, 1);
    VMW(2);
    BARX;

    for (int it = 0; it < nIt; ++it) {
        const int kt1 = 2 * it + 1;
        const bool last = (it == nIt - 1);
        // ---- half 0: consume b0 (kt0) ----
        loadA4(0, 0); loadB2q(0, 0); stageA(kt1, 1, 0);
        BARX; MQ8(0, 0); BARX;
        loadB2q(0, 1); stageA(kt1, 1, 1);
        BARX; MQ8(0, 1); BARX;
        loadA4(0, 1); if (!last) stageB(kt1 + 1, 0, 0);
        BARX; MQ8(1, 0); BARX;
        if (!last) stageB(kt1 + 1, 0, 1);
        BARX; MQ8(1, 1);
        if (last) { VMW(0); } else { VMW(2); }
        BARX;
        // ---- half 1: consume b1 (kt1) ----
        loadA4(1, 0); loadB2q(1, 0); if (!last) stageA(kt1 + 1, 0, 0);
        BARX; MQ8(0, 0); BARX;
        loadB2q(1, 1); if (!last) stageA(kt1 + 1, 0, 1);
        BARX; MQ8(0, 1); BARX;
        loadA4(1, 1); if (!last) stageB(kt1 + 2, 1, 0);
        BARX; MQ8(1, 0); BARX;
        if (!last) stageB(kt1 + 2, 1, 1);
        BARX; MQ8(1, 1);
        if (!last) { VMW(2); }
        BARX;
    }

    float bv[4];
    #pragma unroll
    for (int fc = 0; fc < 4; ++fc)
        bv[fc] = bias ? bias[bn + wc * 64 + fc * 16 + r15] : 0.0f;

    #pragma unroll
    for (int fr = 0; fr < 8; ++fr) {
        #pragma unroll
        for (int q2 = 0; q2 < 4; ++q2) {
            int row = bm + wr * 128 + fr * 16 + ksel * 4 + q2;
            if (row >= M) continue;
            #pragma unroll
            for (int fc = 0; fc < 4; ++fc) {
                int col = bn + wc * 64 + fc * 16 + r15;
                float v = acc[fr][fc][q2] + bv[fc];
                size_t off = (size_t)row * Nc + col;
                if (accumulate) v += Cf[off];
                if (do_relu) v = fmaxf(v, 0.0f);
                if (Cf) Cf[off] = v;
                if (Cb) Cb[off] = __float2bfloat16(v);
            }
        }
    }
}

extern "C" void kernel_launch(void* const* d_in, const int* in_sizes, int n_in,
                              void* d_out, int out_size, void* d_ws, size_t ws_size,
                              hipStream_t stream) {
    const float* x     = (const float*)d_in[0];
    const void*  eidx  = d_in[1];
    const void*  etype = d_in[2];
    const float* w1    = (const float*)d_in[3];
    const float* root1 = (const float*)d_in[4];
    const float* b1    = (const float*)d_in[5];
    const float* w2    = (const float*)d_in[6];
    const float* root2 = (const float*)d_in[7];
    const float* b2    = (const float*)d_in[8];

    float* h_out = (float*)d_out;
    float* emb   = (float*)d_out + (size_t)N_NODES * F_OUT;

    char* ws = (char*)d_ws;
    size_t off = 0;
    auto take = [&](size_t bytes) { char* p = ws + off; off = (off + bytes + 255) & ~(size_t)255; return p; };
    int*      flag    = (int*)take(256);
    unsigned* cnt8    = (unsigned*)take((size_t)NSEG * 4);   // cnt8 + cursor contiguous
    int*      cursor  = (int*)take((size_t)NSEG * 4);
    float*    invc    = (float*)take((size_t)NSEG * 4);
    int*      soff    = (int*)take(((size_t)NSEG + 1) * 4);
    int*      bsum    = (int*)take((size_t)SCAN_NB * 4);
    unsigned* ebuf    = (unsigned*)take((size_t)N_EDGES * 4);
    __hip_bfloat16* xb   = (__hip_bfloat16*)take((size_t)N_NODES * F_IN * 2);
    __hip_bfloat16* embb = (__hip_bfloat16*)take((size_t)N_NODES * F_HID * 2);
    __hip_bfloat16* bt1  = (__hip_bfloat16*)take((size_t)F_HID * KT1 * 2);
    __hip_bfloat16* bt2  = (__hip_bfloat16*)take((size_t)NC2P * F_HID * 2);

    size_t avail = (ws_size > off) ? (ws_size - off) : 0;
    size_t agg8bytes = (size_t)N_NODES * N_REL * F_IN * 2;   // 204.8 MB
    size_t zbytes    = (size_t)N_NODES * NC2P * 2;           // 128 MB
    int CR = (avail >= agg8bytes) ? 8 : 4;
    size_t ubytes = agg8bytes > zbytes ? agg8bytes : zbytes;
    if (CR == 4) ubytes = zbytes;
    char* uni = take(ubytes);
    __hip_bfloat16* aggb = (__hip_bfloat16*)uni;
    __hip_bfloat16* z    = (__hip_bfloat16*)uni;

    detect64_kernel<<<1, 64, 0, stream>>>((const int*)etype, flag);
    (void)hipMemsetAsync(cnt8, 0, (size_t)NSEG * 8, stream);   // cnt8 + cursor
    count_kernel<<<(N_EDGES + 255) / 256, 256, 0, stream>>>(etype, eidx, flag, cnt8);
    scan1_kernel<<<SCAN_NB, 1024, 0, stream>>>(cnt8, invc, soff, bsum);
    scan2_kernel<<<1, 512, 0, stream>>>(bsum);
    scan3_kernel<<<(NSEG + 1023) / 1024, 1024, 0, stream>>>(soff, bsum);
    build_kernel<<<(N_EDGES + 255) / 256, 256, 0, stream>>>(eidx, etype, flag, soff, cursor, ebuf);

    cvt_bf16_kernel<<<(N_NODES * F_IN / 4 + 255) / 256, 256, 0, stream>>>(
        x, xb, (long long)N_NODES * F_IN / 4);
    trans_w_kernel<<<9 * 128 + 9 * 64, 256, 0, stream>>>(w1, root1, w2, root2, bt1, bt2);

    const int MBLKQ = (N_NODES + QBM - 1) / QBM;      // 196
    const int GWAVE_BLOCKS = (N_NODES * 64 + 255) / 256;

    // ---------------- layer 1 (256x256 BK=32 GEMM, 2 blocks/CU) ----------------
    for (int r0 = 0; r0 < N_REL; r0 += CR) {
        if (CR == 8)
            gather1_kernel<8><<<GWAVE_BLOCKS, 256, 0, stream>>>(xb, ebuf, soff, invc, aggb, r0);
        else
            gather1_kernel<4><<<GWAVE_BLOCKS, 256, 0, stream>>>(xb, ebuf, soff, invc, aggb, r0);
        int first = (r0 == 0), last = (r0 + CR >= N_REL);
        int gX = F_HID / QBN, nwg = gX * MBLKQ;
        gemm256_kernel<<<nwg, 512, 0, stream>>>(
            aggb, CR * F_IN, CR * F_IN,
            first ? xb : nullptr, first ? F_IN : 0, F_IN,
            bt1 + (size_t)r0 * F_IN, bt1 + (size_t)N_REL * F_IN, KT1,
            first ? b1 : nullptr,
            emb, last ? embb : nullptr,
            N_NODES, F_HID, first ? 0 : 1, last ? 1 : 0,
            gX, nwg);
    }

    // ---------------- layer 2 (same kernel, Nc=1280 padded) ----------------
    {
        int gX = NC2P / QBN, nwg = gX * MBLKQ;        // 980
        gemm256_kernel<<<nwg, 512, 0, stream>>>(
            embb, F_HID, F_HID, nullptr, 0, 0,
            bt2, nullptr, F_HID,
            nullptr, nullptr, z, N_NODES, NC2P, 0, 0,
            gX, nwg);
    }

    gather2_kernel<<<GWAVE_BLOCKS, 256, 0, stream>>>(z, ebuf, soff, invc, b2, h_out);
}

// Round 15
// 538.312 us; speedup vs baseline: 3.8610x; 3.8610x over previous
//
#include <hip/hip_runtime.h>
#include <hip/hip_bf16.h>
#include <cstddef>
#include <cstdint>

#define N_NODES 50000
#define N_EDGES 800000
#define N_REL 8
#define F_IN 256
#define F_HID 512
#define F_OUT 128
#define KT1 (N_REL * F_IN + F_IN)    // 2304
#define NC2P 1280                    // padded layer-2 cols (1152 used)
#define NSEG (N_NODES * N_REL)       // 400000
#define SCAN_NB ((NSEG + 1023) / 1024) // 391

typedef __attribute__((ext_vector_type(8))) short short8;
typedef __attribute__((ext_vector_type(4))) float f32x4;

__device__ __forceinline__ float bf2f(unsigned short u) {
    return __uint_as_float(((unsigned)u) << 16);
}
__device__ __forceinline__ unsigned short f2bf(float f) {
    __hip_bfloat16 h = __float2bfloat16(f);
    return *reinterpret_cast<unsigned short*>(&h);
}

// ---------- int64-vs-int32 edge dtype detection ----------
__global__ void detect64_kernel(const int* __restrict__ et, int* __restrict__ flag) {
    int v = et[2 * threadIdx.x + 1];
    unsigned long long any = __ballot(v != 0);
    if (threadIdx.x == 0) flag[0] = (any == 0ULL) ? 1 : 0;
}

__device__ __forceinline__ long long ld_idx(const void* __restrict__ p, size_t i, int is64) {
    return is64 ? ((const long long*)p)[i] : (long long)((const int*)p)[i];
}

__global__ void count_kernel(const void* __restrict__ etype, const void* __restrict__ eidx,
                             const int* __restrict__ flag, unsigned* __restrict__ cnt8) {
    int e = blockIdx.x * blockDim.x + threadIdx.x;
    if (e >= N_EDGES) return;
    int is64 = flag[0];
    long long rt  = ld_idx(etype, e, is64);
    long long dst = ld_idx(eidx, (size_t)N_EDGES + e, is64);
    atomicAdd(&cnt8[dst * N_REL + rt], 1u);
}

// ---------- parallel seg-level exclusive scan (3 kernels) + invc ----------
__global__ __launch_bounds__(1024) void scan1_kernel(const unsigned* __restrict__ cnt8,
                                                     float* __restrict__ invc,
                                                     int* __restrict__ soff,
                                                     int* __restrict__ bsum) {
    __shared__ int lds[1024];
    int t = threadIdx.x;
    int i = blockIdx.x * 1024 + t;
    int c = (i < NSEG) ? (int)cnt8[i] : 0;
    if (i < NSEG) invc[i] = 1.0f / (float)(c ? c : 1);
    lds[t] = c;
    __syncthreads();
    for (int o = 1; o < 1024; o <<= 1) {
        int v = (t >= o) ? lds[t - o] : 0;
        __syncthreads();
        lds[t] += v;
        __syncthreads();
    }
    if (i < NSEG) soff[i] = lds[t] - c;
    if (t == 1023) bsum[blockIdx.x] = lds[1023];
}

__global__ __launch_bounds__(512) void scan2_kernel(int* __restrict__ bsum) {
    __shared__ int lds[512];
    int t = threadIdx.x;
    int v = (t < SCAN_NB) ? bsum[t] : 0;
    lds[t] = v;
    __syncthreads();
    for (int o = 1; o < 512; o <<= 1) {
        int x = (t >= o) ? lds[t - o] : 0;
        __syncthreads();
        lds[t] += x;
        __syncthreads();
    }
    if (t < SCAN_NB) bsum[t] = lds[t] - v;
}

__global__ void scan3_kernel(int* __restrict__ soff, const int* __restrict__ bsum) {
    int g = blockIdx.x * blockDim.x + threadIdx.x;
    if (g < NSEG) soff[g] += bsum[g >> 10];
    if (g == 0) soff[NSEG] = N_EDGES;
}

// ---------- bucket edges into seg-sorted CSR: ebuf[pos] = src ----------
__global__ void build_kernel(const void* __restrict__ eidx, const void* __restrict__ etype,
                             const int* __restrict__ flag, const int* __restrict__ soff,
                             int* __restrict__ cursor, unsigned* __restrict__ ebuf) {
    int e = blockIdx.x * blockDim.x + threadIdx.x;
    if (e >= N_EDGES) return;
    int is64 = flag[0];
    int rt  = (int)ld_idx(etype, e, is64);
    int src = (int)ld_idx(eidx, e, is64);
    int dst = (int)ld_idx(eidx, (size_t)N_EDGES + e, is64);
    int seg = dst * N_REL + rt;
    int pos = soff[seg] + atomicAdd(&cursor[seg], 1);
    ebuf[pos] = (unsigned)src;
}

__global__ void cvt_bf16_kernel(const float* __restrict__ in, __hip_bfloat16* __restrict__ out,
                                long long n4) {
    long long g = (long long)blockIdx.x * blockDim.x + threadIdx.x;
    if (g >= n4) return;
    float4 v = ((const float4*)in)[g];
    unsigned short o[4];
    o[0] = f2bf(v.x); o[1] = f2bf(v.y); o[2] = f2bf(v.z); o[3] = f2bf(v.w);
    *(short4*)&out[4 * g] = *(const short4*)o;
}

// ---------- fused LDS-tiled weight transposes ----------
__global__ __launch_bounds__(256) void trans_w_kernel(
    const float* __restrict__ w1, const float* __restrict__ root1,
    const float* __restrict__ w2, const float* __restrict__ root2,
    __hip_bfloat16* __restrict__ bt1, __hip_bfloat16* __restrict__ bt2)
{
    __shared__ float t[32][33];
    int tx = threadIdx.x & 31, ty = threadIdx.x >> 5;
    int b = blockIdx.x;
    if (b < 9 * 128) {
        int r  = b >> 7;
        int rem = b & 127;
        int kt = rem >> 4, nt = rem & 15;
        const float* src = (r < 8) ? (w1 + (size_t)r * F_IN * F_HID) : root1;
        int k0 = kt * 32, n0 = nt * 32;
        #pragma unroll
        for (int i = 0; i < 4; ++i)
            t[ty + i * 8][tx] = src[(size_t)(k0 + ty + i * 8) * F_HID + n0 + tx];
        __syncthreads();
        #pragma unroll
        for (int i = 0; i < 4; ++i) {
            int n = n0 + ty + i * 8;
            bt1[(size_t)n * KT1 + r * F_IN + k0 + tx] = __float2bfloat16(t[tx][ty + i * 8]);
        }
    } else {
        b -= 9 * 128;
        int r  = b >> 6;
        int rem = b & 63;
        int kt = rem >> 2, ot = rem & 3;
        const float* src = (r < 8) ? (w2 + (size_t)r * F_HID * F_OUT) : root2;
        int k0 = kt * 32, o0 = ot * 32;
        #pragma unroll
        for (int i = 0; i < 4; ++i)
            t[ty + i * 8][tx] = src[(size_t)(k0 + ty + i * 8) * F_OUT + o0 + tx];
        __syncthreads();
        #pragma unroll
        for (int i = 0; i < 4; ++i) {
            int o = o0 + ty + i * 8;
            bt2[(size_t)(r * F_OUT + o) * F_HID + k0 + tx] = __float2bfloat16(t[tx][ty + i * 8]);
        }
    }
}

// ---------- layer-1 gather ----------
template <int CR>
__global__ __launch_bounds__(256) void gather1_kernel(
    const __hip_bfloat16* __restrict__ xb, const unsigned* __restrict__ ebuf,
    const int* __restrict__ soff, const float* __restrict__ invc,
    __hip_bfloat16* __restrict__ aggb, int r0)
{
    int wid  = (blockIdx.x * blockDim.x + threadIdx.x) >> 6;
    int lane = threadIdx.x & 63;
    if (wid >= N_NODES) return;
    const int* sp = soff + wid * N_REL + r0;
    int s[CR + 1];
    #pragma unroll
    for (int c = 0; c <= CR; ++c) s[c] = sp[c];

    #pragma unroll
    for (int c = 0; c < CR; ++c) {
        int e0 = s[c], e1 = s[c + 1];
        float a0 = 0.f, a1 = 0.f, a2 = 0.f, a3 = 0.f;
        int e = e0;
        for (; e + 2 <= e1; e += 2) {
            unsigned s0 = ebuf[e], s1 = ebuf[e + 1];
            short4 v0 = *(const short4*)&xb[(size_t)s0 * F_IN + lane * 4];
            short4 v1 = *(const short4*)&xb[(size_t)s1 * F_IN + lane * 4];
            a0 += bf2f((unsigned short)v0.x) + bf2f((unsigned short)v1.x);
            a1 += bf2f((unsigned short)v0.y) + bf2f((unsigned short)v1.y);
            a2 += bf2f((unsigned short)v0.z) + bf2f((unsigned short)v1.z);
            a3 += bf2f((unsigned short)v0.w) + bf2f((unsigned short)v1.w);
        }
        if (e < e1) {
            unsigned s0 = ebuf[e];
            short4 v0 = *(const short4*)&xb[(size_t)s0 * F_IN + lane * 4];
            a0 += bf2f((unsigned short)v0.x);
            a1 += bf2f((unsigned short)v0.y);
            a2 += bf2f((unsigned short)v0.z);
            a3 += bf2f((unsigned short)v0.w);
        }
        float sc = invc[(size_t)wid * N_REL + r0 + c];
        unsigned short o[4];
        o[0] = f2bf(a0 * sc); o[1] = f2bf(a1 * sc);
        o[2] = f2bf(a2 * sc); o[3] = f2bf(a3 * sc);
        *(short4*)&aggb[((size_t)wid * CR + c) * F_IN + lane * 4] = *(const short4*)o;
    }
}

// ---------- layer-2 gather + root + bias + log_softmax ----------
__global__ __launch_bounds__(256) void gather2_kernel(
    const __hip_bfloat16* __restrict__ z, const unsigned* __restrict__ ebuf,
    const int* __restrict__ soff, const float* __restrict__ invc,
    const float* __restrict__ b2, float* __restrict__ h)
{
    int wid  = (blockIdx.x * blockDim.x + threadIdx.x) >> 6;
    int lane = threadIdx.x & 63;
    if (wid >= N_NODES) return;
    const int* sp = soff + wid * N_REL;
    int s[N_REL + 1];
    #pragma unroll
    for (int c = 0; c <= N_REL; ++c) s[c] = sp[c];

    unsigned rv = *(const unsigned*)&z[(size_t)wid * NC2P + N_REL * F_OUT + lane * 2];
    float a0 = bf2f((unsigned short)(rv & 0xffffu)) + b2[lane * 2];
    float a1 = bf2f((unsigned short)(rv >> 16))     + b2[lane * 2 + 1];

    #pragma unroll
    for (int c = 0; c < N_REL; ++c) {
        int e0 = s[c], e1 = s[c + 1];
        float t0 = 0.f, t1 = 0.f;
        const size_t coloff = (size_t)c * F_OUT + lane * 2;
        int e = e0;
        for (; e + 2 <= e1; e += 2) {
            unsigned s0 = ebuf[e], s1 = ebuf[e + 1];
            unsigned pv0 = *(const unsigned*)&z[(size_t)s0 * NC2P + coloff];
            unsigned pv1 = *(const unsigned*)&z[(size_t)s1 * NC2P + coloff];
            t0 += bf2f((unsigned short)(pv0 & 0xffffu)) + bf2f((unsigned short)(pv1 & 0xffffu));
            t1 += bf2f((unsigned short)(pv0 >> 16))     + bf2f((unsigned short)(pv1 >> 16));
        }
        if (e < e1) {
            unsigned s0 = ebuf[e];
            unsigned pv0 = *(const unsigned*)&z[(size_t)s0 * NC2P + coloff];
            t0 += bf2f((unsigned short)(pv0 & 0xffffu));
            t1 += bf2f((unsigned short)(pv0 >> 16));
        }
        float sc = invc[(size_t)wid * N_REL + c];
        a0 = fmaf(sc, t0, a0);
        a1 = fmaf(sc, t1, a1);
    }

    float m = fmaxf(a0, a1);
    #pragma unroll
    for (int o = 32; o > 0; o >>= 1) m = fmaxf(m, __shfl_xor(m, o));
    float sum = expf(a0 - m) + expf(a1 - m);
    #pragma unroll
    for (int o = 32; o > 0; o >>= 1) sum += __shfl_xor(sum, o);
    float lse = m + logf(sum);
    h[(size_t)wid * F_OUT + lane * 2]     = a0 - lse;
    h[(size_t)wid * F_OUT + lane * 2 + 1] = a1 - lse;
}

#define BARX do { __builtin_amdgcn_s_barrier(); __builtin_amdgcn_sched_barrier(0); } while (0)
#define VMW(N) asm volatile("s_waitcnt vmcnt(" #N ")" ::: "memory")

// ================= 256x256 8-wave 8-phase counted-vmcnt GEMM (verified R9-R13) =================
#define QBM 256
#define QBN 256
#define QBK 64

#define MQ256(QR, QC) do {                                                         \
    __builtin_amdgcn_s_setprio(1);                                                 \
    _Pragma("unroll") for (int i2 = 0; i2 < 4; ++i2)                               \
    _Pragma("unroll") for (int j2 = 0; j2 < 2; ++j2)                               \
    _Pragma("unroll") for (int h = 0; h < 2; ++h)                                  \
        acc[(QR)*4 + i2][(QC)*2 + j2] = __builtin_amdgcn_mfma_f32_16x16x32_bf16(   \
            a[i2][h], b[(QC)*2 + j2][h], acc[(QR)*4 + i2][(QC)*2 + j2], 0, 0, 0);  \
    __builtin_amdgcn_s_setprio(0); } while (0)

__global__ __launch_bounds__(512, 1) void gemm256_kernel(
    const __hip_bfloat16* __restrict__ A1, int K1, int lda1,
    const __hip_bfloat16* __restrict__ A2, int K2, int lda2,
    const __hip_bfloat16* __restrict__ BTa, const __hip_bfloat16* __restrict__ BTb, int ldbt,
    const float* __restrict__ bias,
    float* __restrict__ Cf, __hip_bfloat16* __restrict__ Cb,
    int M, int Nc, int accumulate, int do_relu,
    int gridX, int nwg)
{
    __shared__ __align__(16) __hip_bfloat16 As[2][2 * 8192];
    __shared__ __align__(16) __hip_bfloat16 Bs[2][2 * 8192];

    int bid = blockIdx.x;
    int qq = nwg >> 3, rr = nwg & 7;
    int xcd = bid & 7, ii = bid >> 3;
    int wg = (xcd < rr ? xcd * (qq + 1) : rr * (qq + 1) + (xcd - rr) * qq) + ii;
    const int bm = (wg / gridX) * QBM;
    const int bn = (wg % gridX) * QBN;

    const int tid  = threadIdx.x;
    const int lane = tid & 63;
    const int wv   = tid >> 6;
    const int wr   = wv >> 2;
    const int wc   = wv & 3;
    const int r15  = lane & 15;
    const int ksel = lane >> 4;
    const int rsw  = (r15 & 7) << 3;

    const int srow = tid >> 3;
    const int swz8 = ((tid & 7) ^ (srow & 7)) * 8;

    const int Ktot = K1 + K2;
    const int nT   = Ktot / QBK;
    const int nIt  = nT / 2;

    auto stageA = [&](int kt, int bi, int hh) {
        int k0 = kt * QBK;
        const __hip_bfloat16* base = A1; int ld = lda1;
        if (k0 >= K1) { base = A2; ld = lda2; k0 -= K1; }
        #pragma unroll
        for (int c = 0; c < 2; ++c) {
            int gr = bm + hh * 128 + c * 64 + srow; if (gr >= M) gr = M - 1;
            const __hip_bfloat16* gp = base + (size_t)gr * ld + k0 + swz8;
            __builtin_amdgcn_global_load_lds(
                (const __attribute__((address_space(1))) void*)gp,
                (__attribute__((address_space(3))) void*)&As[bi][hh * 8192 + c * 4096 + tid * 8],
                16, 0, 0);
        }
    };
    auto stageB = [&](int kt, int bi, int hh) {
        int k0 = kt * QBK;
        const __hip_bfloat16* base = BTa;
        if (k0 >= K1) { base = BTb; k0 -= K1; }
        #pragma unroll
        for (int c = 0; c < 2; ++c) {
            int n0 = bn + hh * 128 + c * 64 + srow;
            const __hip_bfloat16* gp = base + (size_t)n0 * ldbt + k0 + swz8;
            __builtin_amdgcn_global_load_lds(
                (const __attribute__((address_space(1))) void*)gp,
                (__attribute__((address_space(3))) void*)&Bs[bi][hh * 8192 + c * 4096 + tid * 8],
                16, 0, 0);
        }
    };

    short8 a[4][2], b[4][2];
    auto loadA4 = [&](int bi, int qr) {
        #pragma unroll
        for (int i2 = 0; i2 < 4; ++i2)
            #pragma unroll
            for (int h = 0; h < 2; ++h)
                a[i2][h] = *(const short8*)&As[bi][wr * 8192 +
                    ((qr * 4 + i2) * 16 + r15) * 64 + ((h * 32 + ksel * 8) ^ rsw)];
    };
    auto loadB2q = [&](int bi, int qc) {
        #pragma unroll
        for (int j2 = 0; j2 < 2; ++j2)
            #pragma unroll
            for (int h = 0; h < 2; ++h)
                b[qc * 2 + j2][h] = *(const short8*)&Bs[bi][(wc >> 1) * 8192 +
                    ((wc & 1) * 64 + (qc * 2 + j2) * 16 + r15) * 64 +
                    ((h * 32 + ksel * 8) ^ rsw)];
    };

    f32x4 acc[8][4] = {};

    stageA(0, 0, 0); stageA(0, 0, 1); stageB(0, 0, 0); stageB(0, 0, 1);
    stageB(1, 1, 0); stageB(1, 1, 1);
    VMW(4);
    BARX;

    for (int it = 0; it < nIt; ++it) {
        const int kt1 = 2 * it + 1;
        const bool last = (it == nIt - 1);
        loadA4(0, 0); loadB2q(0, 0); stageA(kt1, 1, 0);
        BARX; MQ256(0, 0); BARX;
        loadB2q(0, 1); stageA(kt1, 1, 1);
        BARX; MQ256(0, 1); BARX;
        loadA4(0, 1); if (!last) stageB(kt1 + 1, 0, 0);
        BARX; MQ256(1, 0); BARX;
        if (!last) stageB(kt1 + 1, 0, 1);
        BARX; MQ256(1, 1);
        if (last) { VMW(0); } else { VMW(4); }
        BARX;
        loadA4(1, 0); loadB2q(1, 0); if (!last) stageA(kt1 + 1, 0, 0);
        BARX; MQ256(0, 0); BARX;
        loadB2q(1, 1); if (!last) stageA(kt1 + 1, 0, 1);
        BARX; MQ256(0, 1); BARX;
        loadA4(1, 1); if (!last) stageB(kt1 + 2, 1, 0);
        BARX; MQ256(1, 0); BARX;
        if (!last) stageB(kt1 + 2, 1, 1);
        BARX; MQ256(1, 1);
        if (!last) { VMW(4); }
        BARX;
    }

    float bv[4];
    #pragma unroll
    for (int fc = 0; fc < 4; ++fc)
        bv[fc] = bias ? bias[bn + wc * 64 + fc * 16 + r15] : 0.0f;

    #pragma unroll
    for (int fr = 0; fr < 8; ++fr) {
        #pragma unroll
        for (int q2 = 0; q2 < 4; ++q2) {
            int row = bm + wr * 128 + fr * 16 + ksel * 4 + q2;
            if (row >= M) continue;
            #pragma unroll
            for (int fc = 0; fc < 4; ++fc) {
                int col = bn + wc * 64 + fc * 16 + r15;
                float v = acc[fr][fc][q2] + bv[fc];
                size_t off = (size_t)row * Nc + col;
                if (accumulate) v += Cf[off];
                if (do_relu) v = fmaxf(v, 0.0f);
                if (Cf) Cf[off] = v;
                if (Cb) Cb[off] = __float2bfloat16(v);
            }
        }
    }
}

extern "C" void kernel_launch(void* const* d_in, const int* in_sizes, int n_in,
                              void* d_out, int out_size, void* d_ws, size_t ws_size,
                              hipStream_t stream) {
    const float* x     = (const float*)d_in[0];
    const void*  eidx  = d_in[1];
    const void*  etype = d_in[2];
    const float* w1    = (const float*)d_in[3];
    const float* root1 = (const float*)d_in[4];
    const float* b1    = (const float*)d_in[5];
    const float* w2    = (const float*)d_in[6];
    const float* root2 = (const float*)d_in[7];
    const float* b2    = (const float*)d_in[8];

    float* h_out = (float*)d_out;
    float* emb   = (float*)d_out + (size_t)N_NODES * F_OUT;

    char* ws = (char*)d_ws;
    size_t off = 0;
    auto take = [&](size_t bytes) { char* p = ws + off; off = (off + bytes + 255) & ~(size_t)255; return p; };
    int*      flag    = (int*)take(256);
    unsigned* cnt8    = (unsigned*)take((size_t)NSEG * 4);   // cnt8 + cursor contiguous:
    int*      cursor  = (int*)take((size_t)NSEG * 4);        // one memset covers both
    float*    invc    = (float*)take((size_t)NSEG * 4);
    int*      soff    = (int*)take(((size_t)NSEG + 1) * 4);
    int*      bsum    = (int*)take((size_t)SCAN_NB * 4);
    unsigned* ebuf    = (unsigned*)take((size_t)N_EDGES * 4);
    __hip_bfloat16* xb   = (__hip_bfloat16*)take((size_t)N_NODES * F_IN * 2);
    __hip_bfloat16* embb = (__hip_bfloat16*)take((size_t)N_NODES * F_HID * 2);
    __hip_bfloat16* bt1  = (__hip_bfloat16*)take((size_t)F_HID * KT1 * 2);
    __hip_bfloat16* bt2  = (__hip_bfloat16*)take((size_t)NC2P * F_HID * 2);

    size_t avail = (ws_size > off) ? (ws_size - off) : 0;
    size_t agg8bytes = (size_t)N_NODES * N_REL * F_IN * 2;   // 204.8 MB
    size_t zbytes    = (size_t)N_NODES * NC2P * 2;           // 128 MB
    int CR = (avail >= agg8bytes) ? 8 : 4;
    size_t ubytes = agg8bytes > zbytes ? agg8bytes : zbytes;
    if (CR == 4) ubytes = zbytes;
    char* uni = take(ubytes);
    __hip_bfloat16* aggb = (__hip_bfloat16*)uni;
    __hip_bfloat16* z    = (__hip_bfloat16*)uni;

    detect64_kernel<<<1, 64, 0, stream>>>((const int*)etype, flag);
    (void)hipMemsetAsync(cnt8, 0, (size_t)NSEG * 8, stream);   // cnt8 + cursor in one shot
    count_kernel<<<(N_EDGES + 255) / 256, 256, 0, stream>>>(etype, eidx, flag, cnt8);
    scan1_kernel<<<SCAN_NB, 1024, 0, stream>>>(cnt8, invc, soff, bsum);
    scan2_kernel<<<1, 512, 0, stream>>>(bsum);
    scan3_kernel<<<(NSEG + 1023) / 1024, 1024, 0, stream>>>(soff, bsum);
    build_kernel<<<(N_EDGES + 255) / 256, 256, 0, stream>>>(eidx, etype, flag, soff, cursor, ebuf);

    cvt_bf16_kernel<<<(N_NODES * F_IN / 4 + 255) / 256, 256, 0, stream>>>(
        x, xb, (long long)N_NODES * F_IN / 4);
    trans_w_kernel<<<9 * 128 + 9 * 64, 256, 0, stream>>>(w1, root1, w2, root2, bt1, bt2);

    const int MBLKQ = (N_NODES + QBM - 1) / QBM;      // 196
    const int GWAVE_BLOCKS = (N_NODES * 64 + 255) / 256;

    // ---------------- layer 1 (256x256 8-wave 8-phase GEMM) ----------------
    for (int r0 = 0; r0 < N_REL; r0 += CR) {
        if (CR == 8)
            gather1_kernel<8><<<GWAVE_BLOCKS, 256, 0, stream>>>(xb, ebuf, soff, invc, aggb, r0);
        else
            gather1_kernel<4><<<GWAVE_BLOCKS, 256, 0, stream>>>(xb, ebuf, soff, invc, aggb, r0);
        int first = (r0 == 0), last = (r0 + CR >= N_REL);
        int gX = F_HID / QBN, nwg = gX * MBLKQ;
        gemm256_kernel<<<nwg, 512, 0, stream>>>(
            aggb, CR * F_IN, CR * F_IN,
            first ? xb : nullptr, first ? F_IN : 0, F_IN,
            bt1 + (size_t)r0 * F_IN, bt1 + (size_t)N_REL * F_IN, KT1,
            first ? b1 : nullptr,
            emb, last ? embb : nullptr,
            N_NODES, F_HID, first ? 0 : 1, last ? 1 : 0,
            gX, nwg);
    }

    // ---------------- layer 2 (same 256x256 kernel, Nc=1280 padded) ----------------
    {
        int gX = NC2P / QBN, nwg = gX * MBLKQ;        // 980
        gemm256_kernel<<<nwg, 512, 0, stream>>>(
            embb, F_HID, F_HID, nullptr, 0, 0,
            bt2, nullptr, F_HID,
            nullptr, nullptr, z, N_NODES, NC2P, 0, 0,
            gX, nwg);
    }

    gather2_kernel<<<GWAVE_BLOCKS, 256, 0, stream>>>(z, ebuf, soff, invc, b2, h_out);
}